// Round 1
// baseline (21.168 us; speedup 1.0000x reference)
//
#include <hip/hip_runtime.h>

// QNN_Q3: 3-qubit StronglyEntanglingLayers circuit, B=128, T=64, D=96,
// n_layers=3 (sequential, rewired), nb=32 blocks, vqc_depth L=2.
// One thread = one circuit (8 complex amps in registers).
// 32 threads per (b,t); 8 (b,t) pairs per 256-thread block; H in LDS.

struct cpx { float re, im; };

__device__ __forceinline__ cpx cmul(cpx a, cpx b) {
    cpx r; r.re = a.re * b.re - a.im * b.im; r.im = a.re * b.im + a.im * b.re; return r;
}

// Apply Rot(phi, theta, omega) = RZ(omega) RY(theta) RZ(phi) on the wire with
// flat-index bit `bit` (wire0->4, wire1->2, wire2->1).
__device__ __forceinline__ void rot_apply(cpx psi[8], float phi, float tht, float omg, int bit) {
    float st, ct; __sincosf(0.5f * tht, &st, &ct);
    float sa, ca; __sincosf(-0.5f * (phi + omg), &sa, &ca);  // a = ca + i*sa
    float sb, cb; __sincosf(0.5f * (phi - omg), &sb, &cb);   // b = cb + i*sb
    cpx U00 = { ca * ct,  sa * ct };
    cpx U01 = { -cb * st, -sb * st };
    cpx U10 = { cb * st,  -sb * st };   // conj(b)*st
    cpx U11 = { ca * ct,  -sa * ct };   // conj(a)*ct
#pragma unroll
    for (int i = 0; i < 8; ++i) {
        if (i & bit) continue;
        cpx p0 = psi[i], p1 = psi[i | bit];
        cpx a0 = cmul(U00, p0), b0 = cmul(U01, p1);
        cpx a1 = cmul(U10, p0), b1 = cmul(U11, p1);
        psi[i].re = a0.re + b0.re;       psi[i].im = a0.im + b0.im;
        psi[i | bit].re = a1.re + b1.re; psi[i | bit].im = a1.im + b1.im;
    }
}

__device__ __forceinline__ void cnot(cpx psi[8], int cb, int tb) {
#pragma unroll
    for (int i = 0; i < 8; ++i) {
        if ((i & cb) && !(i & tb)) {
            cpx tmp = psi[i]; psi[i] = psi[i | tb]; psi[i | tb] = tmp;
        }
    }
}

// One 3-qubit circuit: AngleEmbedding(RY) + 2 layers of (3 Rot + 3 CNOT ring).
// th points to 18 floats: [vl][q][{phi,theta,omega}].
__device__ __forceinline__ void circuit(const float ang[3], const float* __restrict__ th,
                                        float out[3]) {
    float c[3], s[3];
#pragma unroll
    for (int q = 0; q < 3; ++q) __sincosf(0.5f * ang[q], &s[q], &c[q]);
    cpx psi[8];
#pragma unroll
    for (int i = 0; i < 8; ++i) {
        float v = ((i & 4) ? s[0] : c[0]) * ((i & 2) ? s[1] : c[1]) * ((i & 1) ? s[2] : c[2]);
        psi[i].re = v; psi[i].im = 0.0f;
    }
#pragma unroll
    for (int vl = 0; vl < 2; ++vl) {
#pragma unroll
        for (int q = 0; q < 3; ++q) {
            const float* p = th + (vl * 3 + q) * 3;
            rot_apply(psi, p[0], p[1], p[2], 4 >> q);
        }
        int r = vl + 1;  // ranges: (vl % 2) + 1
#pragma unroll
        for (int q = 0; q < 3; ++q) {
            int cb = 4 >> q;
            int tb = 4 >> ((q + r) % 3);
            cnot(psi, cb, tb);
        }
    }
    float p[8];
#pragma unroll
    for (int i = 0; i < 8; ++i) p[i] = psi[i].re * psi[i].re + psi[i].im * psi[i].im;
    out[0] = (p[0] + p[1] + p[2] + p[3]) - (p[4] + p[5] + p[6] + p[7]);
    out[1] = (p[0] + p[1] + p[4] + p[5]) - (p[2] + p[3] + p[6] + p[7]);
    out[2] = (p[0] + p[2] + p[4] + p[6]) - (p[1] + p[3] + p[5] + p[7]);
}

#define PAIRS_PER_BLOCK 8

__global__ __launch_bounds__(256) void qnn_q3_kernel(const float* __restrict__ x,
                                                     const float* __restrict__ theta,
                                                     float* __restrict__ out) {
    const int T = 64, D = 96;
    __shared__ float H[PAIRS_PER_BLOCK][96];

    const int pair = threadIdx.x >> 5;   // which (b,t) in this block
    const int i = threadIdx.x & 31;      // circuit/block index within (b,t)
    const int bt = blockIdx.x * PAIRS_PER_BLOCK + pair;  // b*T + t
    const int t = bt % T;

    // ---- layer 0: contiguous 3-wide blocks of x ----
    const float* xp = x + (size_t)bt * D;
    float ang[3] = { xp[3 * i], xp[3 * i + 1], xp[3 * i + 2] };
    float res[3];
    {
        const float* th = theta + (((size_t)t * 3 + 0) * 32 + i) * 18;
        circuit(ang, th, res);
    }
    H[pair][3 * i] = res[0]; H[pair][3 * i + 1] = res[1]; H[pair][3 * i + 2] = res[2];
    __syncthreads();

    // ---- layers 1..2: rewired reads [3i-1, 3i+1, 3i+3] mod 96 ----
#pragma unroll
    for (int l = 1; l < 3; ++l) {
        const int j0 = (3 * i + 95) % 96;
        const int j1 = (3 * i + 1) % 96;
        const int j2 = (3 * i + 3) % 96;
        ang[0] = H[pair][j0]; ang[1] = H[pair][j1]; ang[2] = H[pair][j2];
        __syncthreads();  // all reads of previous H done before overwrite
        const float* th = theta + (((size_t)t * 3 + l) * 32 + i) * 18;
        circuit(ang, th, res);
        if (l == 2) {
            float* op = out + (size_t)bt * D;
            op[3 * i] = res[0]; op[3 * i + 1] = res[1]; op[3 * i + 2] = res[2];
        } else {
            H[pair][3 * i] = res[0]; H[pair][3 * i + 1] = res[1]; H[pair][3 * i + 2] = res[2];
            __syncthreads();
        }
    }
}

extern "C" void kernel_launch(void* const* d_in, const int* in_sizes, int n_in,
                              void* d_out, int out_size, void* d_ws, size_t ws_size,
                              hipStream_t stream) {
    const float* x = (const float*)d_in[0];       // (128, 64, 96) f32
    const float* theta = (const float*)d_in[1];   // (64, 3, 32, 2, 3, 3) f32
    float* out = (float*)d_out;                   // (128, 64, 96) f32

    const int BT = 128 * 64;                      // 8192 (b,t) pairs
    const int blocks = BT / PAIRS_PER_BLOCK;      // 1024
    qnn_q3_kernel<<<blocks, 256, 0, stream>>>(x, theta, out);
}